// Round 3
// baseline (741.319 us; speedup 1.0000x reference)
//
#include <hip/hip_runtime.h>

#define IN_F   8192
#define OUT_F  16384
#define BATCH  32
#define NWAVE  8                 // waves per block = split-K ways
#define KSLICE (IN_F / NWAVE)    // 1024 K per wave

typedef __attribute__((ext_vector_type(8))) short  bf16x8;
typedef __attribute__((ext_vector_type(4))) float  f32x4;

// fp32 -> bf16 bits, round-to-nearest-even
__device__ __forceinline__ unsigned f2bf(float f) {
    unsigned u = __builtin_bit_cast(unsigned, f);
    return (u + 0x7fffu + ((u >> 16) & 1u)) >> 16;
}

// Exact bf16 pack of two ints in [0,256): (float)i has zero low-16 mantissa
// bits, so bf16 = high half of the fp32 bits, no rounding.
__device__ __forceinline__ unsigned pk_i2bf(int a, int b) {
    unsigned fa = __builtin_bit_cast(unsigned, (float)a);
    unsigned fb = __builtin_bit_cast(unsigned, (float)b);
#if __has_builtin(__builtin_amdgcn_perm)
    return __builtin_amdgcn_perm(fb, fa, 0x07060302u);  // {fb.hi, fa.hi}
#else
    return (fa >> 16) | (fb & 0xffff0000u);
#endif
}

// xbf[b][k] = bf16(x[b][k] * s), sumx[b] = sum_k x[b][k];  s = lut[129]
// (lut is exactly linear: lut[c] = (c-128)*s, so idx can stay integer in bf16)
__global__ __launch_bounds__(256) void prep_kernel(
        const float* __restrict__ x, const float* __restrict__ lut,
        unsigned short* __restrict__ xbf, float* __restrict__ sumx) {
    const int b = blockIdx.x;
    const int t = threadIdx.x;
    const float s = lut[129];
    const float4* xr = (const float4*)(x + b * IN_F);
    ushort4* xo = (ushort4*)(xbf + b * IN_F);
    float acc = 0.f;
    #pragma unroll
    for (int i = 0; i < IN_F / 4 / 256; ++i) {
        float4 v = xr[t + i * 256];
        acc += v.x + v.y + v.z + v.w;
        ushort4 o;
        o.x = (unsigned short)f2bf(v.x * s);
        o.y = (unsigned short)f2bf(v.y * s);
        o.z = (unsigned short)f2bf(v.z * s);
        o.w = (unsigned short)f2bf(v.w * s);
        xo[t + i * 256] = o;
    }
    __shared__ float red[256];
    red[t] = acc;
    __syncthreads();
    for (int off = 128; off > 0; off >>= 1) {
        if (t < off) red[t] += red[t + off];
        __syncthreads();
    }
    if (t == 0) sumx[b] = red[0];
}

// Block = one 16-col n-tile, 8 waves split K. Software-pipelined idx stream.
// MFMA 16x16x32 bf16: A[m=lane&15][k=(lane>>4)*8+j], C/D col=lane&15,
// row=(lane>>4)*4+reg (validated rounds 1-2). Epilogue: LDS cross-wave
// reduce + direct store of bias + lut[0]*sumx[m] + acc (no atomics, no init).
__global__ __launch_bounds__(512, 6) void gemm_kernel(
        const unsigned short* __restrict__ xbf,
        const int* __restrict__ widx,
        const float* __restrict__ bias,
        const float* __restrict__ lut,
        const float* __restrict__ sumx,
        float* __restrict__ out) {
    __shared__ float part[NWAVE * 512];

    const int tid   = threadIdx.x;
    const int wave  = tid >> 6;
    const int lane  = tid & 63;
    const int col16 = lane & 15;
    const int quad  = lane >> 4;
    const int ntile = blockIdx.x;
    const int n     = ntile * 16 + col16;
    const int k0    = wave * KSLICE + quad * 8;

    const int* wp = widx + (long)n * IN_F + k0;
    const unsigned short* xp0 = xbf + col16 * IN_F + k0;   // m = col16
    const unsigned short* xp1 = xp0 + 16 * IN_F;           // m = col16+16

    f32x4 acc0 = {0.f, 0.f, 0.f, 0.f};
    f32x4 acc1 = {0.f, 0.f, 0.f, 0.f};

    // stage 0 preload
    int4   c0 = *(const int4*)wp;
    int4   c1 = *(const int4*)(wp + 4);
    bf16x8 a0 = *(const bf16x8*)xp0;
    bf16x8 a1 = *(const bf16x8*)xp1;

    #pragma unroll 2
    for (int kk = 32; kk < KSLICE; kk += 32) {
        // prefetch next stage before consuming current
        int4   p0 = *(const int4*)(wp + kk);
        int4   p1 = *(const int4*)(wp + kk + 4);
        bf16x8 q0 = *(const bf16x8*)(xp0 + kk);
        bf16x8 q1 = *(const bf16x8*)(xp1 + kk);

        union { unsigned u[4]; bf16x8 v; } bB;
        bB.u[0] = pk_i2bf(c0.x, c0.y);
        bB.u[1] = pk_i2bf(c0.z, c0.w);
        bB.u[2] = pk_i2bf(c1.x, c1.y);
        bB.u[3] = pk_i2bf(c1.z, c1.w);
        acc0 = __builtin_amdgcn_mfma_f32_16x16x32_bf16(a0, bB.v, acc0, 0, 0, 0);
        acc1 = __builtin_amdgcn_mfma_f32_16x16x32_bf16(a1, bB.v, acc1, 0, 0, 0);

        c0 = p0; c1 = p1; a0 = q0; a1 = q1;
    }
    {   // epilogue stage
        union { unsigned u[4]; bf16x8 v; } bB;
        bB.u[0] = pk_i2bf(c0.x, c0.y);
        bB.u[1] = pk_i2bf(c0.z, c0.w);
        bB.u[2] = pk_i2bf(c1.x, c1.y);
        bB.u[3] = pk_i2bf(c1.z, c1.w);
        acc0 = __builtin_amdgcn_mfma_f32_16x16x32_bf16(a0, bB.v, acc0, 0, 0, 0);
        acc1 = __builtin_amdgcn_mfma_f32_16x16x32_bf16(a1, bB.v, acc1, 0, 0, 0);
    }

    // cross-wave split-K reduction in LDS
    #pragma unroll
    for (int r = 0; r < 4; ++r) {
        part[wave * 512 + (quad * 4 + r) * 16 + col16]        = acc0[r];
        part[wave * 512 + (quad * 4 + r + 16) * 16 + col16]   = acc1[r];
    }
    __syncthreads();

    {   // one output element per thread: m = tid>>4 (batch), nn = tid&15
        const int m = tid >> 4, nn = tid & 15;
        float ssum = 0.f;
        #pragma unroll
        for (int w = 0; w < NWAVE; ++w) ssum += part[w * 512 + tid];
        float o = bias[ntile * 16 + nn] + lut[0] * sumx[m] + ssum;
        out[(long)m * OUT_F + ntile * 16 + nn] = o;
    }
}

extern "C" void kernel_launch(void* const* d_in, const int* in_sizes, int n_in,
                              void* d_out, int out_size, void* d_ws, size_t ws_size,
                              hipStream_t stream) {
    const float* x    = (const float*)d_in[0];
    const float* lut  = (const float*)d_in[1];
    const float* bias = (const float*)d_in[2];
    const int*   widx = (const int*)d_in[3];
    float* out = (float*)d_out;

    unsigned short* xbf = (unsigned short*)d_ws;                    // 512 KiB
    float* sumx = (float*)((char*)d_ws + BATCH * IN_F * 2);         // 128 B

    prep_kernel<<<BATCH, 256, 0, stream>>>(x, lut, xbf, sumx);
    gemm_kernel<<<OUT_F / 16, 512, 0, stream>>>(xbf, widx, bias, lut, sumx, out);
}

// Round 4
// 707.461 us; speedup vs baseline: 1.0479x; 1.0479x over previous
//
#include <hip/hip_runtime.h>

#define IN_F   8192
#define OUT_F  16384
#define BATCH  32
#define KBLKS  2                      // split-K across blocks
#define NWAVE  4                      // waves per block (split-K within block)
#define KSLICE (IN_F / KBLKS / NWAVE) // 1024 K per wave

typedef __attribute__((ext_vector_type(8))) short  bf16x8;
typedef __attribute__((ext_vector_type(4))) float  f32x4;

// fp32 -> bf16 bits, round-to-nearest-even
__device__ __forceinline__ unsigned f2bf(float f) {
    unsigned u = __builtin_bit_cast(unsigned, f);
    return (u + 0x7fffu + ((u >> 16) & 1u)) >> 16;
}

// Exact bf16 pack of two ints in [0,256): (float)i has zero low-16 mantissa
// bits, so bf16 = high half of the fp32 bits, no rounding.
__device__ __forceinline__ unsigned pk_i2bf(int a, int b) {
    unsigned fa = __builtin_bit_cast(unsigned, (float)a);
    unsigned fb = __builtin_bit_cast(unsigned, (float)b);
#if __has_builtin(__builtin_amdgcn_perm)
    return __builtin_amdgcn_perm(fb, fa, 0x07060302u);  // {fb.hi, fa.hi}
#else
    return (fa >> 16) | (fb & 0xffff0000u);
#endif
}

// xbf[b][k] = bf16(x[b][k] * s), sumx[b] = sum_k x[b][k];  s = lut[129]
// (lut is exactly linear: lut[c] = (c-128)*s, so idx can stay integer in bf16)
__global__ __launch_bounds__(256) void prep_kernel(
        const float* __restrict__ x, const float* __restrict__ lut,
        unsigned short* __restrict__ xbf, float* __restrict__ sumx) {
    const int b = blockIdx.x;
    const int t = threadIdx.x;
    const float s = lut[129];
    const float4* xr = (const float4*)(x + b * IN_F);
    ushort4* xo = (ushort4*)(xbf + b * IN_F);
    float acc = 0.f;
    #pragma unroll
    for (int i = 0; i < IN_F / 4 / 256; ++i) {
        float4 v = xr[t + i * 256];
        acc += v.x + v.y + v.z + v.w;
        ushort4 o;
        o.x = (unsigned short)f2bf(v.x * s);
        o.y = (unsigned short)f2bf(v.y * s);
        o.z = (unsigned short)f2bf(v.z * s);
        o.w = (unsigned short)f2bf(v.w * s);
        xo[t + i * 256] = o;
    }
    __shared__ float red[256];
    red[t] = acc;
    __syncthreads();
    for (int off = 128; off > 0; off >>= 1) {
        if (t < off) red[t] += red[t + off];
        __syncthreads();
    }
    if (t == 0) sumx[b] = red[0];
}

// out[b][o] = bias[o] + lut[0] * sumx[b]   (lut[0] = -128*s; clears 0xAA poison)
__global__ __launch_bounds__(256) void init_kernel(
        const float* __restrict__ bias, const float* __restrict__ lut,
        const float* __restrict__ sumx, float* __restrict__ out) {
    int i = blockIdx.x * 256 + threadIdx.x;   // over 131072 float4s
    int b = i >> 12;                          // OUT_F/4 = 4096 float4s per row
    float corr = lut[0] * sumx[b];
    const float4* b4 = (const float4*)bias;
    float4 v = b4[i & 4095];
    v.x += corr; v.y += corr; v.z += corr; v.w += corr;
    ((float4*)out)[i] = v;
}

// Grid = 1024 n-tiles x 2 K-halves; 4 waves/block split K further.
// Lean body (~60 VGPR) + launch_bounds(256,8) -> 8 blocks/CU = 32 waves/CU
// for max outstanding idx loads. No LDS; split-K combined via fp32 HW atomics.
// MFMA 16x16x32 bf16: A[m=lane&15][k=(lane>>4)*8+j], C/D col=lane&15,
// row=(lane>>4)*4+reg (validated rounds 1-3).
__global__ __launch_bounds__(256, 8) void gemm_kernel(
        const unsigned short* __restrict__ xbf,
        const int* __restrict__ widx,
        float* __restrict__ out) {
    const int tid   = threadIdx.x;
    const int wave  = tid >> 6;
    const int lane  = tid & 63;
    const int col16 = lane & 15;
    const int quad  = lane >> 4;
    const int ntile = blockIdx.x >> 1;          // 0..1023
    const int kblk  = blockIdx.x & 1;           // 0..1
    const int n     = ntile * 16 + col16;
    const int k0    = (kblk * NWAVE + wave) * KSLICE + quad * 8;

    const int* wp = widx + (long)n * IN_F + k0;
    const unsigned short* xp0 = xbf + col16 * IN_F + k0;   // m = col16
    const unsigned short* xp1 = xp0 + 16 * IN_F;           // m = col16+16

    f32x4 acc0 = {0.f, 0.f, 0.f, 0.f};
    f32x4 acc1 = {0.f, 0.f, 0.f, 0.f};

    #pragma unroll 2
    for (int kk = 0; kk < KSLICE; kk += 32) {
        int4   c0 = *(const int4*)(wp + kk);
        int4   c1 = *(const int4*)(wp + kk + 4);
        bf16x8 a0 = *(const bf16x8*)(xp0 + kk);
        bf16x8 a1 = *(const bf16x8*)(xp1 + kk);

        union { unsigned u[4]; bf16x8 v; } bB;
        bB.u[0] = pk_i2bf(c0.x, c0.y);
        bB.u[1] = pk_i2bf(c0.z, c0.w);
        bB.u[2] = pk_i2bf(c1.x, c1.y);
        bB.u[3] = pk_i2bf(c1.z, c1.w);
        acc0 = __builtin_amdgcn_mfma_f32_16x16x32_bf16(a0, bB.v, acc0, 0, 0, 0);
        acc1 = __builtin_amdgcn_mfma_f32_16x16x32_bf16(a1, bB.v, acc1, 0, 0, 0);
    }

    const int row = quad * 4;
    float* op = out + (long)ntile * 16 + col16;
    #pragma unroll
    for (int r = 0; r < 4; ++r) {
        unsafeAtomicAdd(op + (long)(row + r) * OUT_F,      acc0[r]);
        unsafeAtomicAdd(op + (long)(row + r + 16) * OUT_F, acc1[r]);
    }
}

extern "C" void kernel_launch(void* const* d_in, const int* in_sizes, int n_in,
                              void* d_out, int out_size, void* d_ws, size_t ws_size,
                              hipStream_t stream) {
    const float* x    = (const float*)d_in[0];
    const float* lut  = (const float*)d_in[1];
    const float* bias = (const float*)d_in[2];
    const int*   widx = (const int*)d_in[3];
    float* out = (float*)d_out;

    unsigned short* xbf = (unsigned short*)d_ws;                    // 512 KiB
    float* sumx = (float*)((char*)d_ws + BATCH * IN_F * 2);         // 128 B

    prep_kernel<<<BATCH, 256, 0, stream>>>(x, lut, xbf, sumx);
    init_kernel<<<(BATCH * OUT_F / 4) / 256, 256, 0, stream>>>(bias, lut, sumx, out);
    gemm_kernel<<<OUT_F / 16 * KBLKS, 256, 0, stream>>>(xbf, widx, out);
}